// Round 1
// baseline (11396.835 us; speedup 1.0000x reference)
//
#include <hip/hip_runtime.h>
#include <stdint.h>
#include <math.h>

// ============================================================================
// RBM contrastive divergence (K_GIBBS=1), B=64 sequential steps.
// Low-rank restructure: W_t = W0 + LR * sum_{s<t} (v0_s hinit_s^T - v_s hbin_s^T)
//  h_t  = sig(b_t + C[t] + LR*sum_s(hinit_s*G0[s][t] - hbin_s*GV[s][t]))
//  v_t  = sig(a_t + W0 h_t + LR*sum_s(v0_s*(hinit_s.h_t) - v_s*(hbin_s.h_t)))
// where C = V0 @ W0 (precomputed GEMM), G0 = V0 V0^T, GV[s][t] = v_s . v0_t.
// Only W0*h_t requires a full pass over W0 (65 x 201MB = 13.1 GB total traffic
// vs 51.5 GB for the naive materialized-W version).
// ============================================================================

#define NB   64
#define FLAT 12288
#define HID  4096
#define LRf  0.01f
#define LRd  0.01

// RNG mode: 0 = jax_threefry_partitionable semantics (JAX >= 0.4.36 default)
//           1 = original threefry split/random_bits (older JAX)
// If validation fails with large errors, flip this to 1 next round.
#define RNG_MODE 0

// ---- workspace layout (byte offsets) ----
#define OFF_KEYS   0u          // 64*4 u32   (kbin0,kbin1,kinit0,kinit1 per step)
#define OFF_B      1024u       // 4096 f32   b_cur
#define OFF_A      17408u      // 12288 f32  a_cur
#define OFF_H      66560u      // 4096 f32   h_cur
#define OFF_AL     82944u      // 64 f64     alpha (hinit_s . h)
#define OFF_BE     83456u      // 64 f64     beta  (hbin_s . h)
#define OFF_G0     83968u      // 64*64 f64  v0_s . v0_t
#define OFF_GV     116736u     // 64*64 f64  v_s . v0_t
#define OFF_HIB    149504u     // 64*128 u32 hinit bitmasks
#define OFF_HBB    182272u     // 64*128 u32 hbin bitmasks
#define OFF_C      215040u     // 64*4096 f32  C = V0 @ W0
#define OFF_V      1263616u    // 64*12288 f32 reconstructed v_s
#define OFF_CPART  4409344u    // NCH*64*4096 f32 partials for C GEMM

// ---------------------------------------------------------------------------
// Threefry-2x32, 20 rounds (matches jax._src.prng)
// ---------------------------------------------------------------------------
__device__ __forceinline__ void tf(uint32_t k0, uint32_t k1,
                                   uint32_t x0, uint32_t x1,
                                   uint32_t& o0, uint32_t& o1) {
  uint32_t ks[3] = {k0, k1, k0 ^ k1 ^ 0x1BD11BDAu};
  x0 += ks[0]; x1 += ks[1];
  const int R0[4] = {13, 15, 26, 6};
  const int R1[4] = {17, 29, 16, 24};
#pragma unroll
  for (int i = 0; i < 5; ++i) {
    const int* r = (i & 1) ? R1 : R0;
#pragma unroll
    for (int q = 0; q < 4; ++q) {
      x0 += x1;
      x1 = (x1 << r[q]) | (x1 >> (32 - r[q]));
      x1 ^= x0;
    }
    x0 += ks[(i + 1) % 3];
    x1 += ks[(i + 2) % 3] + (uint32_t)(i + 1);
  }
  o0 = x0; o1 = x1;
}

// bits -> uniform [0,1): bitcast((bits>>9)|0x3f800000) - 1.0f  (jax uniform)
__device__ __forceinline__ float u01(uint32_t bits) {
  uint32_t fb = (bits >> 9) | 0x3f800000u;
  return __uint_as_float(fb) - 1.0f;
}

// ---------------------------------------------------------------------------
// setup: copy a,b into ws; derive per-step (kbin,kinit) key table
// ---------------------------------------------------------------------------
__global__ void k_setup(const float* a_in, const float* b_in,
                        float* a_cur, float* b_cur, uint32_t* keys4) {
  int gid = blockIdx.x * blockDim.x + threadIdx.x;
  int stride = gridDim.x * blockDim.x;
  for (int i = gid; i < FLAT; i += stride) a_cur[i] = a_in[i];
  for (int i = gid; i < HID; i += stride) b_cur[i] = b_in[i];
  if (gid < NB) {
    uint32_t t = (uint32_t)gid;
    uint32_t kt0, kt1, o0, o1, p0, p1;
#if RNG_MODE == 0
    // partitionable: key_t = tf(root,(0,t)); subkey_i = tf(key_t,(0,i))
    tf(0u, 42u, 0u, t, kt0, kt1);
    tf(kt0, kt1, 0u, 0u, o0, o1);   // kbin  = split(key_t)[0]
    tf(kt0, kt1, 0u, 1u, p0, p1);   // kinit = split(key_t)[1]
    keys4[4 * gid + 0] = o0; keys4[4 * gid + 1] = o1;
    keys4[4 * gid + 2] = p0; keys4[4 * gid + 3] = p1;
#else
    // original: counts=iota(128) split in half; key_t=(out[2t],out[2t+1])
    if (t < 32) {
      tf(0u, 42u, 2 * t,     64 + 2 * t, o0, o1); kt0 = o0;
      tf(0u, 42u, 2 * t + 1, 65 + 2 * t, o0, o1); kt1 = o0;
    } else {
      tf(0u, 42u, 2 * t - 64, 2 * t,     o0, o1); kt0 = o1;
      tf(0u, 42u, 2 * t - 63, 2 * t + 1, o0, o1); kt1 = o1;
    }
    // split(key_t): counts [0,1,2,3] -> pairs (0,2),(1,3)
    uint32_t a0, a1, b0, b1;
    tf(kt0, kt1, 0u, 2u, a0, a1);
    tf(kt0, kt1, 1u, 3u, b0, b1);
    keys4[4 * gid + 0] = a0; keys4[4 * gid + 1] = b0;  // kbin
    keys4[4 * gid + 2] = a1; keys4[4 * gid + 3] = b1;  // kinit
#endif
  }
}

// ---------------------------------------------------------------------------
// G0[s][t] = v0_s . v0_t   (one wave per (s,t) pair, f64 accumulate)
// ---------------------------------------------------------------------------
__global__ void k_g0(const float* v0all, double* G0) {
  int w = (blockIdx.x * blockDim.x + threadIdx.x) >> 6;
  int lane = threadIdx.x & 63;
  if (w >= NB * NB) return;
  int s = w >> 6, t = w & 63;
  const float* vs = v0all + (size_t)s * FLAT;
  const float* vt = v0all + (size_t)t * FLAT;
  double acc = 0.0;
  for (int i = lane; i < FLAT; i += 64) acc += (double)vs[i] * (double)vt[i];
  for (int m = 32; m; m >>= 1) acc += __shfl_xor(acc, m, 64);
  if (lane == 0) G0[w] = acc;
}

// ---------------------------------------------------------------------------
// C partial GEMM: Cpart[ich][t][j] = sum_{i in chunk} v0[t][i]*W0[i][j]
// grid (16 j-blocks, 2 t-groups of 32, NCH i-chunks), 256 threads
// ---------------------------------------------------------------------------
#define CG_TPG 32
__global__ __launch_bounds__(256) void k_cgemm(const float* v0all, const float* W0,
                                               float* Cpart, int NCH) {
  int j = blockIdx.x * 256 + threadIdx.x;
  int t0 = blockIdx.y * CG_TPG;
  int ilen = FLAT / NCH;
  int ibeg = blockIdx.z * ilen, iend = ibeg + ilen;
  __shared__ float lv[CG_TPG][64];
  float acc[CG_TPG];
#pragma unroll
  for (int k = 0; k < CG_TPG; ++k) acc[k] = 0.f;
  for (int i0 = ibeg; i0 < iend; i0 += 64) {
    __syncthreads();
    for (int e = threadIdx.x; e < CG_TPG * 64; e += 256) {
      int tt = e >> 6, ii = e & 63;
      lv[tt][ii] = v0all[(size_t)(t0 + tt) * FLAT + i0 + ii];
    }
    __syncthreads();
    for (int ii = 0; ii < 64; ++ii) {
      float w = W0[(size_t)(i0 + ii) * HID + j];
#pragma unroll
      for (int tt = 0; tt < CG_TPG; ++tt) acc[tt] += w * lv[tt][ii];
    }
  }
  for (int tt = 0; tt < CG_TPG; ++tt)
    Cpart[((size_t)blockIdx.z * NB + t0 + tt) * HID + j] = acc[tt];
}

__global__ void k_creduce(const float* Cpart, float* C, int NCH) {
  int gid = blockIdx.x * blockDim.x + threadIdx.x;
  if (gid >= NB * HID) return;
  double s = 0.0;
  for (int c = 0; c < NCH; ++c) s += (double)Cpart[(size_t)c * NB * HID + gid];
  C[gid] = (float)s;
}

// ---------------------------------------------------------------------------
// Per-step hidden-side kernel (single block, 1024 threads):
//   B: h_t = sig(b + C[t] + LR*sum_{s<t}(hinit_bit*G0 - hbin_bit*GV))
//   C: threefry sampling -> bitmask rows (ballot), b update
//   D: alpha[s]=hinit_s.h, beta[s]=hbin_s.h   (for s < smax2)
// t == NB means "final" mode: only phase D with smax2 = NB, h = stored h_63.
// ---------------------------------------------------------------------------
__global__ __launch_bounds__(1024) void k_hid(int t, const float* Call,
                                              const double* G0, const double* GV,
                                              float* b_cur, float* h_cur,
                                              uint32_t* Hib, uint32_t* Hbb,
                                              double* al, double* be,
                                              const uint32_t* keys4) {
  const int tid = threadIdx.x;
  const int wv = tid >> 6, lane = tid & 63;
  const bool fin = (t == NB);
  __shared__ float h_lds[HID];
  __shared__ float u_b[HID];
  __shared__ float u_i[HID];
  __shared__ double g0c[NB];
  __shared__ double gvc[NB];

  if (!fin) {
    // stage G0/GV columns (only s<t entries are consumed)
    for (int s = tid; s < NB; s += 1024) {
      g0c[s] = G0[s * NB + t];
      gvc[s] = GV[s * NB + t];
    }
    __syncthreads();
    // ---- phase B: logits + h ----
    for (int j = tid; j < HID; j += 1024) {
      double lg = (double)b_cur[j] + (double)Call[(size_t)t * HID + j];
      double acc = 0.0;
      int word = j >> 5;
      uint32_t bit = 1u << (j & 31);
      for (int s = 0; s < t; ++s) {
        if (Hib[s * 128 + word] & bit) acc += g0c[s];
        if (Hbb[s * 128 + word] & bit) acc -= gvc[s];
      }
      lg += LRd * acc;
      float h = (float)(1.0 / (1.0 + exp(-lg)));
      h_cur[j] = h;
      h_lds[j] = h;
    }
    __syncthreads();
    // ---- phase C1: uniforms ----
    uint32_t kb0 = keys4[4 * t + 0], kb1 = keys4[4 * t + 1];
    uint32_t ki0 = keys4[4 * t + 2], ki1 = keys4[4 * t + 3];
#if RNG_MODE == 0
    for (int j = tid; j < HID; j += 1024) {
      uint32_t o0, o1;
      tf(kb0, kb1, 0u, (uint32_t)j, o0, o1); u_b[j] = u01(o0 ^ o1);
      tf(ki0, ki1, 0u, (uint32_t)j, o0, o1); u_i[j] = u01(o0 ^ o1);
    }
#else
    for (int m = tid; m < HID / 2; m += 1024) {
      uint32_t o0, o1;
      tf(kb0, kb1, (uint32_t)m, (uint32_t)(m + HID / 2), o0, o1);
      u_b[m] = u01(o0); u_b[m + HID / 2] = u01(o1);
      tf(ki0, ki1, (uint32_t)m, (uint32_t)(m + HID / 2), o0, o1);
      u_i[m] = u01(o0); u_i[m + HID / 2] = u01(o1);
    }
#endif
    __syncthreads();
    // ---- phase C2: ballot bitmasks + b update ----
    for (int k = 0; k < 4; ++k) {
      int j = k * 1024 + tid;
      float p = h_lds[j];
      bool hb = p > u_b[j];
      bool hi = p > u_i[j];
      unsigned long long mb = __ballot(hb);
      unsigned long long mi = __ballot(hi);
      if (lane == 0) {
        int wbase = j >> 5;  // j is 64-aligned for lane 0
        Hbb[t * 128 + wbase]     = (uint32_t)mb;
        Hbb[t * 128 + wbase + 1] = (uint32_t)(mb >> 32);
        Hib[t * 128 + wbase]     = (uint32_t)mi;
        Hib[t * 128 + wbase + 1] = (uint32_t)(mi >> 32);
      }
      b_cur[j] += LRf * ((hi ? 1.f : 0.f) - (hb ? 1.f : 0.f));
    }
    __syncthreads();
  } else {
    for (int j = tid; j < HID; j += 1024) h_lds[j] = h_cur[j];
    __syncthreads();
  }

  // ---- phase D: alpha/beta dots ----
  const int smax2 = fin ? NB : t;
  for (int task = wv; task < 2 * smax2; task += 16) {
    int s = task >> 1;
    const uint32_t* row = (task & 1) ? &Hbb[s * 128] : &Hib[s * 128];
    double acc = 0.0;
    for (int k = 0; k < 64; ++k) {
      int j = k * 64 + lane;
      if (row[j >> 5] & (1u << (j & 31))) acc += (double)h_lds[j];
    }
    for (int m = 32; m; m >>= 1) acc += __shfl_xor(acc, m, 64);
    if (lane == 0) { if (task & 1) be[s] = acc; else al[s] = acc; }
  }
}

// ---------------------------------------------------------------------------
// Big GEMV: v_t = sig(a + W0 h + LR*sum_{s<t}(v0_s*al[s] - v_s*be[s]))
// wave per row; f64 accumulate; fused low-rank correction + a update.
// t == NB: final mode -> write d_out, no state update.
// ---------------------------------------------------------------------------
__global__ __launch_bounds__(256) void k_gemv(int t, const float* W0,
                                              const float* v0all,
                                              const float* h_cur,
                                              const double* al, const double* be,
                                              float* a_cur, float* V, float* out) {
  __shared__ float hs[HID];
  for (int e = threadIdx.x; e < HID / 4; e += 256)
    ((float4*)hs)[e] = ((const float4*)h_cur)[e];
  __syncthreads();
  const int wv = threadIdx.x >> 6, lane = threadIdx.x & 63;
  const int row = blockIdx.x * 4 + wv;
  const int smax = t;  // t==NB -> all 64
  const float4* wr = (const float4*)(W0 + (size_t)row * HID);
  double acc = 0.0;
#pragma unroll
  for (int c = 0; c < 16; ++c) {
    float4 w = wr[c * 64 + lane];
    float4 h = ((const float4*)hs)[c * 64 + lane];
    acc += (double)w.x * h.x + (double)w.y * h.y +
           (double)w.z * h.z + (double)w.w * h.w;
  }
  // low-rank correction: lane handles s = lane
  if (lane < smax) {
    double c = (double)v0all[(size_t)lane * FLAT + row] * al[lane]
             - (double)V[(size_t)lane * FLAT + row] * be[lane];
    acc += LRd * c;
  }
  for (int m = 32; m; m >>= 1) acc += __shfl_xor(acc, m, 64);
  if (lane == 0) {
    double lg = (double)a_cur[row] + acc;
    float v = (float)(1.0 / (1.0 + exp(-lg)));
    if (t == NB) {
      out[row] = v;
    } else {
      V[(size_t)t * FLAT + row] = v;
      a_cur[row] += LRf * (v0all[(size_t)t * FLAT + row] - v);
    }
  }
}

// ---------------------------------------------------------------------------
// GV row t: GV[t][t'] = v_t . v0_t'  for t' > t (one block per t')
// ---------------------------------------------------------------------------
__global__ void k_gv(int t, const float* v0all, const float* V, double* GV) {
  int tp = t + 1 + blockIdx.x;
  const float* vt = V + (size_t)t * FLAT;
  const float* v0 = v0all + (size_t)tp * FLAT;
  double acc = 0.0;
  for (int i = threadIdx.x; i < FLAT; i += 256) acc += (double)vt[i] * (double)v0[i];
  for (int m = 32; m; m >>= 1) acc += __shfl_xor(acc, m, 64);
  __shared__ double red[4];
  int wv = threadIdx.x >> 6, lane = threadIdx.x & 63;
  if (lane == 0) red[wv] = acc;
  __syncthreads();
  if (threadIdx.x == 0) GV[t * NB + tp] = red[0] + red[1] + red[2] + red[3];
}

// ---------------------------------------------------------------------------
extern "C" void kernel_launch(void* const* d_in, const int* in_sizes, int n_in,
                              void* d_out, int out_size, void* d_ws, size_t ws_size,
                              hipStream_t stream) {
  const float* inputs = (const float*)d_in[0];  // (64, 12288) row-major
  const float* W0     = (const float*)d_in[1];  // (12288, 4096) row-major
  const float* a_in   = (const float*)d_in[2];  // (12288,)
  const float* b_in   = (const float*)d_in[3];  // (4096,)
  float* out = (float*)d_out;                   // (12288,)

  char* ws = (char*)d_ws;
  uint32_t* keys4 = (uint32_t*)(ws + OFF_KEYS);
  float* b_cur = (float*)(ws + OFF_B);
  float* a_cur = (float*)(ws + OFF_A);
  float* h_cur = (float*)(ws + OFF_H);
  double* al   = (double*)(ws + OFF_AL);
  double* be   = (double*)(ws + OFF_BE);
  double* G0   = (double*)(ws + OFF_G0);
  double* GV   = (double*)(ws + OFF_GV);
  uint32_t* Hib = (uint32_t*)(ws + OFF_HIB);
  uint32_t* Hbb = (uint32_t*)(ws + OFF_HBB);
  float* C     = (float*)(ws + OFF_C);
  float* V     = (float*)(ws + OFF_V);
  float* Cpart = (float*)(ws + OFF_CPART);

  // pick largest i-chunk count whose partial buffer fits ws
  int NCH = 16;
  while (NCH > 1 &&
         OFF_CPART + (size_t)NCH * NB * HID * sizeof(float) > ws_size)
    NCH >>= 1;

  hipLaunchKernelGGL(k_setup, dim3(48), dim3(256), 0, stream,
                     a_in, b_in, a_cur, b_cur, keys4);
  hipLaunchKernelGGL(k_g0, dim3(1024), dim3(256), 0, stream, inputs, G0);
  hipLaunchKernelGGL(k_cgemm, dim3(16, 2, NCH), dim3(256), 0, stream,
                     inputs, W0, Cpart, NCH);
  hipLaunchKernelGGL(k_creduce, dim3((NB * HID + 255) / 256), dim3(256), 0,
                     stream, Cpart, C, NCH);

  for (int t = 0; t < NB; ++t) {
    hipLaunchKernelGGL(k_hid, dim3(1), dim3(1024), 0, stream,
                       t, C, G0, GV, b_cur, h_cur, Hib, Hbb, al, be, keys4);
    hipLaunchKernelGGL(k_gemv, dim3(FLAT / 4), dim3(256), 0, stream,
                       t, W0, inputs, h_cur, al, be, a_cur, V, out);
    if (t < NB - 1)
      hipLaunchKernelGGL(k_gv, dim3(NB - 1 - t), dim3(256), 0, stream,
                         t, inputs, V, GV);
  }
  // final: v = sig(a_f + W_f h_63)
  hipLaunchKernelGGL(k_hid, dim3(1), dim3(1024), 0, stream,
                     NB, C, G0, GV, b_cur, h_cur, Hib, Hbb, al, be, keys4);
  hipLaunchKernelGGL(k_gemv, dim3(FLAT / 4), dim3(256), 0, stream,
                     NB, W0, inputs, h_cur, al, be, a_cur, V, out);
}

// Round 5
// 6476.227 us; speedup vs baseline: 1.7598x; 1.7598x over previous
//
#include <hip/hip_runtime.h>
#include <stdint.h>
#include <math.h>

// ============================================================================
// RBM contrastive divergence (K_GIBBS=1), B=64 sequential steps.
// Low-rank restructure: W_t = W0 + LR * sum_{s<t} (v0_s hinit_s^T - v_s hbin_s^T)
//  h_t  = sig(b_t + C[t] + LR*sum_s(hinit_s*G0[s][t] - hbin_s*GV[s][t]))
//  v_t  = sig(a_t + W0 h_t + LR*sum_s(v0_s*(hinit_s.h_t) - v_s*(hbin_s.h_t)))
// C = V0 @ W0 (one GEMM), G0 = V0 V0^T, GV[s][t] = v_s . v0_t.
// Only W0*h_t touches W0 (65 x 201MB total) -> HBM floor ~2.1ms.
// ============================================================================

#define NB   64
#define FLAT 12288
#define HID  4096
#define LRf  0.01f
#define LRd  0.01
#define RNG_MODE 0

// ---- workspace layout (byte offsets) ----
#define OFF_KEYS   0u          // 64*4 u32
#define OFF_B      1024u       // 4096 f32
#define OFF_A      17408u      // 12288 f32
#define OFF_H      66560u      // 4096 f32
#define OFF_ALP    82944u      // 16*64 f64 block-partial alpha
#define OFF_BEP    91136u      // 16*64 f64 block-partial beta
#define OFF_G0     99328u      // 64*64 f64
#define OFF_GV     132096u     // 64*64 f64
#define OFF_HIB    164864u     // 64*128 u32 hinit bitmasks
#define OFF_HBB    197632u     // 64*128 u32 hbin bitmasks
#define OFF_C      230400u     // 64*4096 f32
#define OFF_V      1278976u    // 64*12288 f32 (row-major, for k_gv)
#define OFF_VT     4424704u    // 12288*64 f32 (transposed, for gemv correction)
#define OFF_V0T    7570432u    // 12288*64 f32 (transposed v0)
#define OFF_CPART  1278976u    // aliases V/VT/V0T: Cpart dead before V written

// ---------------------------------------------------------------------------
__device__ __forceinline__ void tf(uint32_t k0, uint32_t k1,
                                   uint32_t x0, uint32_t x1,
                                   uint32_t& o0, uint32_t& o1) {
  uint32_t ks[3] = {k0, k1, k0 ^ k1 ^ 0x1BD11BDAu};
  x0 += ks[0]; x1 += ks[1];
  const int R0[4] = {13, 15, 26, 6};
  const int R1[4] = {17, 29, 16, 24};
#pragma unroll
  for (int i = 0; i < 5; ++i) {
    const int* r = (i & 1) ? R1 : R0;
#pragma unroll
    for (int q = 0; q < 4; ++q) {
      x0 += x1;
      x1 = (x1 << r[q]) | (x1 >> (32 - r[q]));
      x1 ^= x0;
    }
    x0 += ks[(i + 1) % 3];
    x1 += ks[(i + 2) % 3] + (uint32_t)(i + 1);
  }
  o0 = x0; o1 = x1;
}

__device__ __forceinline__ float u01(uint32_t bits) {
  uint32_t fb = (bits >> 9) | 0x3f800000u;
  return __uint_as_float(fb) - 1.0f;
}

// ---------------------------------------------------------------------------
__global__ void k_setup(const float* a_in, const float* b_in,
                        float* a_cur, float* b_cur, uint32_t* keys4) {
  int gid = blockIdx.x * blockDim.x + threadIdx.x;
  int stride = gridDim.x * blockDim.x;
  for (int i = gid; i < FLAT; i += stride) a_cur[i] = a_in[i];
  for (int i = gid; i < HID; i += stride) b_cur[i] = b_in[i];
  if (gid < NB) {
    uint32_t t = (uint32_t)gid;
    uint32_t kt0, kt1, o0, o1, p0, p1;
#if RNG_MODE == 0
    tf(0u, 42u, 0u, t, kt0, kt1);
    tf(kt0, kt1, 0u, 0u, o0, o1);
    tf(kt0, kt1, 0u, 1u, p0, p1);
    keys4[4 * gid + 0] = o0; keys4[4 * gid + 1] = o1;
    keys4[4 * gid + 2] = p0; keys4[4 * gid + 3] = p1;
#else
    if (t < 32) {
      tf(0u, 42u, 2 * t,     64 + 2 * t, o0, o1); kt0 = o0;
      tf(0u, 42u, 2 * t + 1, 65 + 2 * t, o0, o1); kt1 = o0;
    } else {
      tf(0u, 42u, 2 * t - 64, 2 * t,     o0, o1); kt0 = o1;
      tf(0u, 42u, 2 * t - 63, 2 * t + 1, o0, o1); kt1 = o1;
    }
    uint32_t a0, a1, b0, b1;
    tf(kt0, kt1, 0u, 2u, a0, a1);
    tf(kt0, kt1, 1u, 3u, b0, b1);
    keys4[4 * gid + 0] = a0; keys4[4 * gid + 1] = b0;
    keys4[4 * gid + 2] = a1; keys4[4 * gid + 3] = b1;
#endif
  }
}

// v0T[i][s] = v0[s][i]
__global__ void k_vt(const float* v0all, float* v0T) {
  int i = blockIdx.x * 256 + threadIdx.x;
#pragma unroll 8
  for (int s = 0; s < NB; ++s)
    v0T[(size_t)i * NB + s] = v0all[(size_t)s * FLAT + i];
}

// ---------------------------------------------------------------------------
// G0: block per s; stage v0_s in LDS; 4 waves cover 64 t's.
// ---------------------------------------------------------------------------
__global__ __launch_bounds__(256) void k_g0(const float* v0all, double* G0) {
  int s = blockIdx.x;
  __shared__ float vs[FLAT];
  for (int e = threadIdx.x; e < FLAT / 4; e += 256)
    ((float4*)vs)[e] = ((const float4*)(v0all + (size_t)s * FLAT))[e];
  __syncthreads();
  int wv = threadIdx.x >> 6, lane = threadIdx.x & 63;
  for (int tt = wv; tt < NB; tt += 4) {
    const float* vt = v0all + (size_t)tt * FLAT;
    double acc = 0.0;
    for (int i = lane; i < FLAT; i += 64) acc += (double)vs[i] * (double)vt[i];
    for (int m = 32; m; m >>= 1) acc += __shfl_xor(acc, m, 64);
    if (lane == 0) G0[s * NB + tt] = acc;
  }
}

// ---------------------------------------------------------------------------
// C partial GEMM v2: block = 64 j x all 64 t. 256 thr = 64 j-lanes x 4 t-thr,
// 16 static f32 accumulators each. v0 tile transposed in LDS ([ii][t], pad 68)
// so fragment reads are float4 broadcasts. W0 read exactly once.
// grid (HID/64, NCH).
// ---------------------------------------------------------------------------
__global__ __launch_bounds__(256) void k_cgemm(const float* v0all, const float* W0,
                                               float* Cpart, int NCH) {
  const int jl = threadIdx.x & 63;
  const int tth = threadIdx.x >> 6;            // 0..3
  const int j = blockIdx.x * 64 + jl;
  const int ilen = FLAT / NCH;
  const int ibeg = blockIdx.y * ilen, iend = ibeg + ilen;
  __shared__ float lv[64 * 68];                // [ii][t], pad 68
  float acc[16];
#pragma unroll
  for (int k = 0; k < 16; ++k) acc[k] = 0.f;
  for (int i0 = ibeg; i0 < iend; i0 += 64) {
    __syncthreads();
    for (int e = threadIdx.x; e < 4096; e += 256) {
      int tt = e >> 6, ii = e & 63;
      lv[ii * 68 + tt] = v0all[(size_t)tt * FLAT + i0 + ii];
    }
    __syncthreads();
#pragma unroll 2
    for (int ii = 0; ii < 64; ++ii) {
      float w = W0[(size_t)(i0 + ii) * HID + j];
      const float* lp = &lv[ii * 68 + tth * 16];
#pragma unroll
      for (int k4 = 0; k4 < 4; ++k4) {
        float4 hv = *(const float4*)(lp + 4 * k4);
        acc[4 * k4 + 0] += w * hv.x;
        acc[4 * k4 + 1] += w * hv.y;
        acc[4 * k4 + 2] += w * hv.z;
        acc[4 * k4 + 3] += w * hv.w;
      }
    }
  }
#pragma unroll
  for (int k = 0; k < 16; ++k)
    Cpart[((size_t)blockIdx.y * NB + tth * 16 + k) * HID + j] = acc[k];
}

__global__ void k_creduce(const float* Cpart, float* C, int NCH) {
  int gid = blockIdx.x * blockDim.x + threadIdx.x;
  if (gid >= NB * HID) return;
  double s = 0.0;
  for (int c = 0; c < NCH; ++c) s += (double)Cpart[(size_t)c * NB * HID + gid];
  C[gid] = (float)s;
}

// ---------------------------------------------------------------------------
// Hidden-side, 16 blocks x 256 thr (one j per thread):
//   h_t = sig(b + C[t] + LR*sum_{s<t}(hib*G0 - hbb*GV)); threefry sample;
//   ballot -> mask row t; b update; block-partial alpha/beta dots for s<=t
//   (s==t uses this block's fresh local samples; partials reduced
//    deterministically inside k_gemv).
// ---------------------------------------------------------------------------
__global__ __launch_bounds__(256) void k_hbc(int t, const float* Call,
                                             const double* G0, const double* GV,
                                             float* b_cur, float* h_cur,
                                             uint32_t* Hib, uint32_t* Hbb,
                                             double* alp, double* bep,
                                             const uint32_t* keys4) {
  const int tid = threadIdx.x;
  const int lane = tid & 63, wv = tid >> 6;
  const int j = blockIdx.x * 256 + tid;
  __shared__ double g0c[NB], gvc[NB];
  __shared__ float h_blk[256];
  __shared__ unsigned char ib_blk[256], bb_blk[256];
  for (int s = tid; s < NB; s += 256) { g0c[s] = G0[s * NB + t]; gvc[s] = GV[s * NB + t]; }
  __syncthreads();
  const int word = j >> 5;
  const uint32_t bit = 1u << (j & 31);
  double acc = 0.0;
  for (int s = 0; s < t; ++s) {
    if (Hib[s * 128 + word] & bit) acc += g0c[s];
    if (Hbb[s * 128 + word] & bit) acc -= gvc[s];
  }
  double lg = (double)b_cur[j] + (double)Call[(size_t)t * HID + j] + LRd * acc;
  float h = (float)(1.0 / (1.0 + exp(-lg)));
  h_cur[j] = h;
  uint32_t o0, o1;
  uint32_t kb0 = keys4[4 * t], kb1 = keys4[4 * t + 1];
  uint32_t ki0 = keys4[4 * t + 2], ki1 = keys4[4 * t + 3];
#if RNG_MODE == 0
  tf(kb0, kb1, 0u, (uint32_t)j, o0, o1); float ub = u01(o0 ^ o1);
  tf(ki0, ki1, 0u, (uint32_t)j, o0, o1); float ui = u01(o0 ^ o1);
#else
  uint32_t m = (uint32_t)(j & (HID / 2 - 1));
  tf(kb0, kb1, m, m + HID / 2, o0, o1); float ub = u01(j < HID / 2 ? o0 : o1);
  tf(ki0, ki1, m, m + HID / 2, o0, o1); float ui = u01(j < HID / 2 ? o0 : o1);
#endif
  bool hb = h > ub, hi = h > ui;
  unsigned long long mb = __ballot(hb), mi = __ballot(hi);
  if (lane == 0) {
    Hbb[t * 128 + word]     = (uint32_t)mb;
    Hbb[t * 128 + word + 1] = (uint32_t)(mb >> 32);
    Hib[t * 128 + word]     = (uint32_t)mi;
    Hib[t * 128 + word + 1] = (uint32_t)(mi >> 32);
  }
  b_cur[j] += LRf * ((hi ? 1.f : 0.f) - (hb ? 1.f : 0.f));
  h_blk[tid] = h; ib_blk[tid] = hi ? 1 : 0; bb_blk[tid] = hb ? 1 : 0;
  __syncthreads();
  // block-partial dots, s <= t
  for (int task = wv; task < 2 * (t + 1); task += 4) {
    int s = task >> 1;
    const uint32_t* row = (task & 1) ? &Hbb[s * 128] : &Hib[s * 128];
    const unsigned char* loc = (task & 1) ? bb_blk : ib_blk;
    double p = 0.0;
#pragma unroll
    for (int q = 0; q < 4; ++q) {
      int jj = q * 64 + lane;
      bool on;
      if (s == t) on = loc[jj] != 0;
      else {
        int gj = blockIdx.x * 256 + jj;
        on = (row[gj >> 5] >> (gj & 31)) & 1u;
      }
      if (on) p += (double)h_blk[jj];
    }
    for (int m2 = 32; m2; m2 >>= 1) p += __shfl_xor(p, m2, 64);
    if (lane == 0) {
      if (task & 1) bep[(size_t)blockIdx.x * NB + s] = p;
      else          alp[(size_t)blockIdx.x * NB + s] = p;
    }
  }
}

// ---------------------------------------------------------------------------
// Big GEMV: 512 thr, 8 rows/block (wave per row), grid FLAT/8.
// alpha/beta partials reduced once per block (fixed order -> deterministic).
// Correction loads coalesced via v0T/Vt. t==NB: final mode, write d_out.
// ---------------------------------------------------------------------------
__global__ __launch_bounds__(512) void k_gemv(int t, const float* W0,
                                              const float* v0T, const float* h_cur,
                                              const double* alp, const double* bep,
                                              float* a_cur, float* V, float* Vt,
                                              float* out) {
  __shared__ float hs[HID];
  __shared__ double als[NB], bes[NB];
  const int tid = threadIdx.x;
  for (int e = tid; e < HID / 4; e += 512)
    ((float4*)hs)[e] = ((const float4*)h_cur)[e];
  if (tid < NB) {
    double asum = 0.0, bsum = 0.0;
#pragma unroll
    for (int b = 0; b < 16; ++b) {
      asum += alp[(size_t)b * NB + tid];
      bsum += bep[(size_t)b * NB + tid];
    }
    als[tid] = asum; bes[tid] = bsum;
  }
  __syncthreads();
  const int wv = tid >> 6, lane = tid & 63;
  const int row = blockIdx.x * 8 + wv;
  const float4* wr = (const float4*)(W0 + (size_t)row * HID);
  double acc = 0.0;
#pragma unroll
  for (int c = 0; c < 16; ++c) {
    float4 w = wr[c * 64 + lane];
    float4 hh = ((const float4*)hs)[c * 64 + lane];
    acc += (double)w.x * hh.x + (double)w.y * hh.y +
           (double)w.z * hh.z + (double)w.w * hh.w;
  }
  const int smax = (t > NB - 1) ? NB : t;
  if (lane < smax) {
    double c = (double)v0T[(size_t)row * NB + lane] * als[lane]
             - (double)Vt[(size_t)row * NB + lane] * bes[lane];
    acc += LRd * c;
  }
  for (int m = 32; m; m >>= 1) acc += __shfl_xor(acc, m, 64);
  if (lane == 0) {
    double lg = (double)a_cur[row] + acc;
    float v = (float)(1.0 / (1.0 + exp(-lg)));
    if (t == NB) {
      out[row] = v;
    } else {
      V[(size_t)t * FLAT + row] = v;
      Vt[(size_t)row * NB + t] = v;
      a_cur[row] += LRf * (v0T[(size_t)row * NB + t] - v);
    }
  }
}

// ---------------------------------------------------------------------------
// GV row t: GV[t][t'] = v_t . v0_t' for t' > t (block per t').
// ---------------------------------------------------------------------------
__global__ void k_gv(int t, const float* v0all, const float* V, double* GV) {
  int tp = t + 1 + blockIdx.x;
  const float* vt = V + (size_t)t * FLAT;
  const float* v0 = v0all + (size_t)tp * FLAT;
  double acc = 0.0;
  for (int i = threadIdx.x; i < FLAT; i += 256) acc += (double)vt[i] * (double)v0[i];
  for (int m = 32; m; m >>= 1) acc += __shfl_xor(acc, m, 64);
  __shared__ double red[4];
  int wv = threadIdx.x >> 6, lane = threadIdx.x & 63;
  if (lane == 0) red[wv] = acc;
  __syncthreads();
  if (threadIdx.x == 0) GV[t * NB + tp] = red[0] + red[1] + red[2] + red[3];
}

// ---------------------------------------------------------------------------
extern "C" void kernel_launch(void* const* d_in, const int* in_sizes, int n_in,
                              void* d_out, int out_size, void* d_ws, size_t ws_size,
                              hipStream_t stream) {
  const float* inputs = (const float*)d_in[0];
  const float* W0     = (const float*)d_in[1];
  const float* a_in   = (const float*)d_in[2];
  const float* b_in   = (const float*)d_in[3];
  float* out = (float*)d_out;

  char* ws = (char*)d_ws;
  uint32_t* keys4 = (uint32_t*)(ws + OFF_KEYS);
  float* b_cur = (float*)(ws + OFF_B);
  float* a_cur = (float*)(ws + OFF_A);
  float* h_cur = (float*)(ws + OFF_H);
  double* alp  = (double*)(ws + OFF_ALP);
  double* bep  = (double*)(ws + OFF_BEP);
  double* G0   = (double*)(ws + OFF_G0);
  double* GV   = (double*)(ws + OFF_GV);
  uint32_t* Hib = (uint32_t*)(ws + OFF_HIB);
  uint32_t* Hbb = (uint32_t*)(ws + OFF_HBB);
  float* C     = (float*)(ws + OFF_C);
  float* V     = (float*)(ws + OFF_V);
  float* Vt    = (float*)(ws + OFF_VT);
  float* v0T   = (float*)(ws + OFF_V0T);
  float* Cpart = (float*)(ws + OFF_CPART);   // aliases V/Vt/v0T (dead after creduce)

  // largest chunk count whose partial buffer fits ws (ilen stays /64)
  int NCH = 16;
  static const int nch_opts[5] = {16, 12, 8, 6, 4};
  for (int i = 0; i < 5; ++i) {
    NCH = nch_opts[i];
    if (OFF_CPART + (size_t)NCH * NB * HID * sizeof(float) <= ws_size) break;
  }

  hipLaunchKernelGGL(k_setup, dim3(48), dim3(256), 0, stream,
                     a_in, b_in, a_cur, b_cur, keys4);
  hipLaunchKernelGGL(k_g0, dim3(NB), dim3(256), 0, stream, inputs, G0);
  hipLaunchKernelGGL(k_cgemm, dim3(HID / 64, NCH), dim3(256), 0, stream,
                     inputs, W0, Cpart, NCH);
  hipLaunchKernelGGL(k_creduce, dim3((NB * HID + 255) / 256), dim3(256), 0,
                     stream, Cpart, C, NCH);
  hipLaunchKernelGGL(k_vt, dim3(FLAT / 256), dim3(256), 0, stream, inputs, v0T);

  for (int t = 0; t < NB; ++t) {
    hipLaunchKernelGGL(k_hbc, dim3(HID / 256), dim3(256), 0, stream,
                       t, C, G0, GV, b_cur, h_cur, Hib, Hbb, alp, bep, keys4);
    hipLaunchKernelGGL(k_gemv, dim3(FLAT / 8), dim3(512), 0, stream,
                       t, W0, v0T, h_cur, alp, bep, a_cur, V, Vt, out);
    if (t < NB - 1)
      hipLaunchKernelGGL(k_gv, dim3(NB - 1 - t), dim3(256), 0, stream,
                         t, inputs, V, GV);
  }
  // final: v = sig(a_64 + W_64 h_63); alpha/beta for s<=63 already from k_hbc(63)
  hipLaunchKernelGGL(k_gemv, dim3(FLAT / 8), dim3(512), 0, stream,
                     NB, W0, v0T, h_cur, alp, bep, a_cur, V, Vt, out);
}

// Round 7
// 4173.141 us; speedup vs baseline: 2.7310x; 1.5519x over previous
//
#include <hip/hip_runtime.h>
#include <stdint.h>
#include <math.h>

// ============================================================================
// RBM contrastive divergence (K_GIBBS=1), B=64 sequential steps.
// Low-rank restructure: W_t = W0 + LR * sum_{s<t} (v0_s hinit_s^T - v_s hbin_s^T)
//  h_t  = sig(b_t + C[t] + LR*sum_s(hinit_s*G0[s][t] - hbin_s*GV[s][t]))
//  v_t  = sig(a_t + W0 h_t + LR*sum_s(v0_s*(hinit_s.h_t) - v_s*(hbin_s.h_t)))
// C = V0 @ W0 (one GEMM), G0 = V0 V0^T, GV[s][t] = v_s . v0_t.
// Only W0*h_t touches W0 (65 x 201MB total) -> HBM floor ~2.1ms.
// ============================================================================

#define NB   64
#define FLAT 12288
#define HID  4096
#define LRf  0.01f
#define LRd  0.01
#define RNG_MODE 0

// ---- workspace layout (byte offsets) ----
#define OFF_KEYS   0u          // 64*4 u32
#define OFF_B      1024u       // 4096 f32
#define OFF_A      17408u      // 12288 f32
#define OFF_H      66560u      // 4096 f32
#define OFF_ALP    82944u      // 16*64 f64 block-partial alpha
#define OFF_BEP    91136u      // 16*64 f64 block-partial beta
#define OFF_G0     99328u      // 64*64 f64
#define OFF_GV     132096u     // 64*64 f64
#define OFF_HIB    164864u     // 64*128 u32 hinit bitmasks (row-major)
#define OFF_HBB    197632u     // 64*128 u32 hbin bitmasks (row-major)
#define OFF_C      230400u     // 64*4096 f32
#define OFF_V      1278976u    // 64*12288 f32 (row-major, for k_gv)
#define OFF_VT     4424704u    // 12288*64 f32 (transposed, for gemv correction)
#define OFF_V0T    7570432u    // 12288*64 f32 (transposed v0)
#define OFF_HIBC   10716160u   // 4096 u64 transposed hinit columns (bit s)
#define OFF_HBBC   10748928u   // 4096 u64 transposed hbin columns
#define OFF_CPART  1278976u    // aliases V/VT/V0T: Cpart dead before V written

// ---------------------------------------------------------------------------
__device__ __forceinline__ void tf(uint32_t k0, uint32_t k1,
                                   uint32_t x0, uint32_t x1,
                                   uint32_t& o0, uint32_t& o1) {
  uint32_t ks[3] = {k0, k1, k0 ^ k1 ^ 0x1BD11BDAu};
  x0 += ks[0]; x1 += ks[1];
  const int R0[4] = {13, 15, 26, 6};
  const int R1[4] = {17, 29, 16, 24};
#pragma unroll
  for (int i = 0; i < 5; ++i) {
    const int* r = (i & 1) ? R1 : R0;
#pragma unroll
    for (int q = 0; q < 4; ++q) {
      x0 += x1;
      x1 = (x1 << r[q]) | (x1 >> (32 - r[q]));
      x1 ^= x0;
    }
    x0 += ks[(i + 1) % 3];
    x1 += ks[(i + 2) % 3] + (uint32_t)(i + 1);
  }
  o0 = x0; o1 = x1;
}

__device__ __forceinline__ float u01(uint32_t bits) {
  uint32_t fb = (bits >> 9) | 0x3f800000u;
  return __uint_as_float(fb) - 1.0f;
}

// ---------------------------------------------------------------------------
__global__ void k_setup(const float* a_in, const float* b_in,
                        float* a_cur, float* b_cur, uint32_t* keys4) {
  int gid = blockIdx.x * blockDim.x + threadIdx.x;
  int stride = gridDim.x * blockDim.x;
  for (int i = gid; i < FLAT; i += stride) a_cur[i] = a_in[i];
  for (int i = gid; i < HID; i += stride) b_cur[i] = b_in[i];
  if (gid < NB) {
    uint32_t t = (uint32_t)gid;
    uint32_t kt0, kt1, o0, o1, p0, p1;
#if RNG_MODE == 0
    tf(0u, 42u, 0u, t, kt0, kt1);
    tf(kt0, kt1, 0u, 0u, o0, o1);
    tf(kt0, kt1, 0u, 1u, p0, p1);
    keys4[4 * gid + 0] = o0; keys4[4 * gid + 1] = o1;
    keys4[4 * gid + 2] = p0; keys4[4 * gid + 3] = p1;
#else
    if (t < 32) {
      tf(0u, 42u, 2 * t,     64 + 2 * t, o0, o1); kt0 = o0;
      tf(0u, 42u, 2 * t + 1, 65 + 2 * t, o0, o1); kt1 = o0;
    } else {
      tf(0u, 42u, 2 * t - 64, 2 * t,     o0, o1); kt0 = o1;
      tf(0u, 42u, 2 * t - 63, 2 * t + 1, o0, o1); kt1 = o1;
    }
    uint32_t a0, a1, b0, b1;
    tf(kt0, kt1, 0u, 2u, a0, a1);
    tf(kt0, kt1, 1u, 3u, b0, b1);
    keys4[4 * gid + 0] = a0; keys4[4 * gid + 1] = b0;
    keys4[4 * gid + 2] = a1; keys4[4 * gid + 3] = b1;
#endif
  }
}

// v0T[i][s] = v0[s][i]
__global__ void k_vt(const float* v0all, float* v0T) {
  int i = blockIdx.x * 256 + threadIdx.x;
#pragma unroll 8
  for (int s = 0; s < NB; ++s)
    v0T[(size_t)i * NB + s] = v0all[(size_t)s * FLAT + i];
}

// ---------------------------------------------------------------------------
// G0 v3: block per (s,t) pair (4096 blocks) — parallelism over reuse.
// v0 is 3MB -> L2-resident after first touch. float4 loads, tree reduce.
// (round-2 version: 64 blocks + wave-serial dep chains = 775us, 2.9% occ)
// ---------------------------------------------------------------------------
__global__ __launch_bounds__(256) void k_g0(const float* v0all, double* G0) {
  const int t = blockIdx.x, s = blockIdx.y;
  const float4* vs = (const float4*)(v0all + (size_t)s * FLAT);
  const float4* vt = (const float4*)(v0all + (size_t)t * FLAT);
  double acc = 0.0;
  for (int e = threadIdx.x; e < FLAT / 4; e += 256) {
    float4 a = vs[e], b = vt[e];
    acc += (double)a.x * b.x + (double)a.y * b.y +
           (double)a.z * b.z + (double)a.w * b.w;
  }
  for (int m = 32; m; m >>= 1) acc += __shfl_xor(acc, m, 64);
  __shared__ double red[4];
  int wv = threadIdx.x >> 6, lane = threadIdx.x & 63;
  if (lane == 0) red[wv] = acc;
  __syncthreads();
  if (threadIdx.x == 0) G0[s * NB + t] = red[0] + red[1] + red[2] + red[3];
}

// ---------------------------------------------------------------------------
// C partial GEMM: block = 64 j x all 64 t. 256 thr = 64 j-lanes x 4 t-thr,
// 16 static f32 accumulators. v0 tile transposed in LDS. grid (HID/64, NCH).
// ---------------------------------------------------------------------------
__global__ __launch_bounds__(256) void k_cgemm(const float* v0all, const float* W0,
                                               float* Cpart, int NCH) {
  const int jl = threadIdx.x & 63;
  const int tth = threadIdx.x >> 6;            // 0..3
  const int j = blockIdx.x * 64 + jl;
  const int ilen = FLAT / NCH;
  const int ibeg = blockIdx.y * ilen, iend = ibeg + ilen;
  __shared__ float lv[64 * 68];                // [ii][t], pad 68
  float acc[16];
#pragma unroll
  for (int k = 0; k < 16; ++k) acc[k] = 0.f;
  for (int i0 = ibeg; i0 < iend; i0 += 64) {
    __syncthreads();
    for (int e = threadIdx.x; e < 4096; e += 256) {
      int tt = e >> 6, ii = e & 63;
      lv[ii * 68 + tt] = v0all[(size_t)tt * FLAT + i0 + ii];
    }
    __syncthreads();
#pragma unroll 2
    for (int ii = 0; ii < 64; ++ii) {
      float w = W0[(size_t)(i0 + ii) * HID + j];
      const float* lp = &lv[ii * 68 + tth * 16];
#pragma unroll
      for (int k4 = 0; k4 < 4; ++k4) {
        float4 hv = *(const float4*)(lp + 4 * k4);
        acc[4 * k4 + 0] += w * hv.x;
        acc[4 * k4 + 1] += w * hv.y;
        acc[4 * k4 + 2] += w * hv.z;
        acc[4 * k4 + 3] += w * hv.w;
      }
    }
  }
#pragma unroll
  for (int k = 0; k < 16; ++k)
    Cpart[((size_t)blockIdx.y * NB + tth * 16 + k) * HID + j] = acc[k];
}

__global__ void k_creduce(const float* Cpart, float* C, int NCH) {
  int gid = blockIdx.x * blockDim.x + threadIdx.x;
  if (gid >= NB * HID) return;
  double s = 0.0;
  for (int c = 0; c < NCH; ++c) s += (double)Cpart[(size_t)c * NB * HID + gid];
  C[gid] = (float)s;
}

// ---------------------------------------------------------------------------
// Hidden-side, 16 blocks x 256 thr (one j per thread):
//  phase B: h_t from transposed mask COLUMNS (2 u64 loads + ctz loop over set
//           bits, g0c/gvc in LDS) — replaces 2t serial global loads/thread.
//  phase C: threefry sample; ballot -> row-mask t; column-bit t; b update.
//  phase D: block-partial alpha/beta dots for s<=t, masks staged in LDS.
// ---------------------------------------------------------------------------
__global__ __launch_bounds__(256) void k_hbc(int t, const float* Call,
                                             const double* G0, const double* GV,
                                             float* b_cur, float* h_cur,
                                             uint32_t* Hib, uint32_t* Hbb,
                                             uint64_t* HibC, uint64_t* HbbC,
                                             double* alp, double* bep,
                                             const uint32_t* keys4) {
  const int tid = threadIdx.x;
  const int lane = tid & 63, wv = tid >> 6;
  const int j = blockIdx.x * 256 + tid;
  __shared__ double g0c[NB], gvc[NB];
  __shared__ float h_blk[256];
  __shared__ unsigned char ib_blk[256], bb_blk[256];
  __shared__ uint32_t ldsI[NB][8], ldsB[NB][8];   // this block's mask words, s<t
  for (int s = tid; s < NB; s += 256) { g0c[s] = G0[s * NB + t]; gvc[s] = GV[s * NB + t]; }
  for (int idx = tid; idx < t * 8; idx += 256) {
    int s = idx >> 3, w = idx & 7;
    ldsI[s][w] = Hib[s * 128 + blockIdx.x * 8 + w];
    ldsB[s][w] = Hbb[s * 128 + blockIdx.x * 8 + w];
  }
  __syncthreads();
  // ---- phase B: logit via transposed columns ----
  uint64_t rawI = (t == 0) ? 0ull : HibC[j];
  uint64_t rawB = (t == 0) ? 0ull : HbbC[j];
  const uint64_t mlow = (t == 0) ? 0ull : ((1ull << t) - 1ull);
  uint64_t mi64 = rawI & mlow, mb64 = rawB & mlow;
  double accp = 0.0, accm = 0.0;
  while (mi64) { int s = __builtin_ctzll(mi64); accp += g0c[s]; mi64 &= mi64 - 1; }
  while (mb64) { int s = __builtin_ctzll(mb64); accm += gvc[s]; mb64 &= mb64 - 1; }
  double lg = (double)b_cur[j] + (double)Call[(size_t)t * HID + j] + LRd * (accp - accm);
  float h = (float)(1.0 / (1.0 + exp(-lg)));
  h_cur[j] = h;
  // ---- phase C: sample ----
  uint32_t o0, o1;
  uint32_t kb0 = keys4[4 * t], kb1 = keys4[4 * t + 1];
  uint32_t ki0 = keys4[4 * t + 2], ki1 = keys4[4 * t + 3];
#if RNG_MODE == 0
  tf(kb0, kb1, 0u, (uint32_t)j, o0, o1); float ub = u01(o0 ^ o1);
  tf(ki0, ki1, 0u, (uint32_t)j, o0, o1); float ui = u01(o0 ^ o1);
#else
  uint32_t m = (uint32_t)(j & (HID / 2 - 1));
  tf(kb0, kb1, m, m + HID / 2, o0, o1); float ub = u01(j < HID / 2 ? o0 : o1);
  tf(ki0, ki1, m, m + HID / 2, o0, o1); float ui = u01(j < HID / 2 ? o0 : o1);
#endif
  bool hb = h > ub, hi = h > ui;
  unsigned long long mb = __ballot(hb), mi = __ballot(hi);
  const int word = j >> 5;
  if (lane == 0) {
    Hbb[t * 128 + word]     = (uint32_t)mb;
    Hbb[t * 128 + word + 1] = (uint32_t)(mb >> 32);
    Hib[t * 128 + word]     = (uint32_t)mi;
    Hib[t * 128 + word + 1] = (uint32_t)(mi >> 32);
  }
  HibC[j] = rawI | ((uint64_t)(hi ? 1 : 0) << t);   // thread j owns word j
  HbbC[j] = rawB | ((uint64_t)(hb ? 1 : 0) << t);
  b_cur[j] += LRf * ((hi ? 1.f : 0.f) - (hb ? 1.f : 0.f));
  h_blk[tid] = h; ib_blk[tid] = hi ? 1 : 0; bb_blk[tid] = hb ? 1 : 0;
  __syncthreads();
  // ---- phase D: block-partial dots, s <= t (masks from LDS) ----
  for (int task = wv; task < 2 * (t + 1); task += 4) {
    int s = task >> 1;
    const bool useB = task & 1;
    double p = 0.0;
#pragma unroll
    for (int q = 0; q < 4; ++q) {
      int jj = q * 64 + lane;
      bool on;
      if (s == t) on = (useB ? bb_blk[jj] : ib_blk[jj]) != 0;
      else {
        uint32_t w32 = useB ? ldsB[s][jj >> 5] : ldsI[s][jj >> 5];
        on = (w32 >> (jj & 31)) & 1u;
      }
      if (on) p += (double)h_blk[jj];
    }
    for (int m2 = 32; m2; m2 >>= 1) p += __shfl_xor(p, m2, 64);
    if (lane == 0) {
      if (useB) bep[(size_t)blockIdx.x * NB + s] = p;
      else      alp[(size_t)blockIdx.x * NB + s] = p;
    }
  }
}

// ---------------------------------------------------------------------------
// Big GEMV: 512 thr, 8 rows/block (wave per row), grid FLAT/8.
// alpha/beta partials reduced once per block (fixed order -> deterministic).
// Correction loads coalesced via v0T/Vt. t==NB: final mode, write d_out.
// ---------------------------------------------------------------------------
__global__ __launch_bounds__(512) void k_gemv(int t, const float* W0,
                                              const float* v0T, const float* h_cur,
                                              const double* alp, const double* bep,
                                              float* a_cur, float* V, float* Vt,
                                              float* out) {
  __shared__ float hs[HID];
  __shared__ double als[NB], bes[NB];
  const int tid = threadIdx.x;
  for (int e = tid; e < HID / 4; e += 512)
    ((float4*)hs)[e] = ((const float4*)h_cur)[e];
  if (tid < NB) {
    double asum = 0.0, bsum = 0.0;
#pragma unroll
    for (int b = 0; b < 16; ++b) {
      asum += alp[(size_t)b * NB + tid];
      bsum += bep[(size_t)b * NB + tid];
    }
    als[tid] = asum; bes[tid] = bsum;
  }
  __syncthreads();
  const int wv = tid >> 6, lane = tid & 63;
  const int row = blockIdx.x * 8 + wv;
  const float4* wr = (const float4*)(W0 + (size_t)row * HID);
  double acc = 0.0;
#pragma unroll
  for (int c = 0; c < 16; ++c) {
    float4 w = wr[c * 64 + lane];
    float4 hh = ((const float4*)hs)[c * 64 + lane];
    acc += (double)w.x * hh.x + (double)w.y * hh.y +
           (double)w.z * hh.z + (double)w.w * hh.w;
  }
  const int smax = (t > NB - 1) ? NB : t;
  if (lane < smax) {
    double c = (double)v0T[(size_t)row * NB + lane] * als[lane]
             - (double)Vt[(size_t)row * NB + lane] * bes[lane];
    acc += LRd * c;
  }
  for (int m = 32; m; m >>= 1) acc += __shfl_xor(acc, m, 64);
  if (lane == 0) {
    double lg = (double)a_cur[row] + acc;
    float v = (float)(1.0 / (1.0 + exp(-lg)));
    if (t == NB) {
      out[row] = v;
    } else {
      V[(size_t)t * FLAT + row] = v;
      Vt[(size_t)row * NB + t] = v;
      a_cur[row] += LRf * (v0T[(size_t)row * NB + t] - v);
    }
  }
}

// ---------------------------------------------------------------------------
// GV row t: GV[t][t'] = v_t . v0_t' for t' > t (block per t'), float4.
// ---------------------------------------------------------------------------
__global__ void k_gv(int t, const float* v0all, const float* V, double* GV) {
  int tp = t + 1 + blockIdx.x;
  const float4* vt = (const float4*)(V + (size_t)t * FLAT);
  const float4* v0 = (const float4*)(v0all + (size_t)tp * FLAT);
  double acc = 0.0;
  for (int e = threadIdx.x; e < FLAT / 4; e += 256) {
    float4 a = vt[e], b = v0[e];
    acc += (double)a.x * b.x + (double)a.y * b.y +
           (double)a.z * b.z + (double)a.w * b.w;
  }
  for (int m = 32; m; m >>= 1) acc += __shfl_xor(acc, m, 64);
  __shared__ double red[4];
  int wv = threadIdx.x >> 6, lane = threadIdx.x & 63;
  if (lane == 0) red[wv] = acc;
  __syncthreads();
  if (threadIdx.x == 0) GV[t * NB + tp] = red[0] + red[1] + red[2] + red[3];
}

// ---------------------------------------------------------------------------
extern "C" void kernel_launch(void* const* d_in, const int* in_sizes, int n_in,
                              void* d_out, int out_size, void* d_ws, size_t ws_size,
                              hipStream_t stream) {
  const float* inputs = (const float*)d_in[0];
  const float* W0     = (const float*)d_in[1];
  const float* a_in   = (const float*)d_in[2];
  const float* b_in   = (const float*)d_in[3];
  float* out = (float*)d_out;

  char* ws = (char*)d_ws;
  uint32_t* keys4 = (uint32_t*)(ws + OFF_KEYS);
  float* b_cur = (float*)(ws + OFF_B);
  float* a_cur = (float*)(ws + OFF_A);
  float* h_cur = (float*)(ws + OFF_H);
  double* alp  = (double*)(ws + OFF_ALP);
  double* bep  = (double*)(ws + OFF_BEP);
  double* G0   = (double*)(ws + OFF_G0);
  double* GV   = (double*)(ws + OFF_GV);
  uint32_t* Hib = (uint32_t*)(ws + OFF_HIB);
  uint32_t* Hbb = (uint32_t*)(ws + OFF_HBB);
  uint64_t* HibC = (uint64_t*)(ws + OFF_HIBC);
  uint64_t* HbbC = (uint64_t*)(ws + OFF_HBBC);
  float* C     = (float*)(ws + OFF_C);
  float* V     = (float*)(ws + OFF_V);
  float* Vt    = (float*)(ws + OFF_VT);
  float* v0T   = (float*)(ws + OFF_V0T);
  float* Cpart = (float*)(ws + OFF_CPART);   // aliases V/Vt/v0T (dead after creduce)

  // largest chunk count whose partial buffer fits ws (ilen stays /64)
  int NCH = 16;
  static const int nch_opts[5] = {16, 12, 8, 6, 4};
  for (int i = 0; i < 5; ++i) {
    NCH = nch_opts[i];
    if (OFF_CPART + (size_t)NCH * NB * HID * sizeof(float) <= ws_size) break;
  }

  hipLaunchKernelGGL(k_setup, dim3(48), dim3(256), 0, stream,
                     a_in, b_in, a_cur, b_cur, keys4);
  hipLaunchKernelGGL(k_g0, dim3(NB, NB), dim3(256), 0, stream, inputs, G0);
  hipLaunchKernelGGL(k_cgemm, dim3(HID / 64, NCH), dim3(256), 0, stream,
                     inputs, W0, Cpart, NCH);
  hipLaunchKernelGGL(k_creduce, dim3((NB * HID + 255) / 256), dim3(256), 0,
                     stream, Cpart, C, NCH);
  hipLaunchKernelGGL(k_vt, dim3(FLAT / 256), dim3(256), 0, stream, inputs, v0T);

  for (int t = 0; t < NB; ++t) {
    hipLaunchKernelGGL(k_hbc, dim3(HID / 256), dim3(256), 0, stream,
                       t, C, G0, GV, b_cur, h_cur, Hib, Hbb, HibC, HbbC,
                       alp, bep, keys4);
    hipLaunchKernelGGL(k_gemv, dim3(FLAT / 8), dim3(512), 0, stream,
                       t, W0, v0T, h_cur, alp, bep, a_cur, V, Vt, out);
    if (t < NB - 1)
      hipLaunchKernelGGL(k_gv, dim3(NB - 1 - t), dim3(256), 0, stream,
                         t, inputs, V, GV);
  }
  // final: v = sig(a_64 + W_64 h_63); alpha/beta for s<=63 already from k_hbc(63)
  hipLaunchKernelGGL(k_gemv, dim3(FLAT / 8), dim3(512), 0, stream,
                     NB, W0, v0T, h_cur, alp, bep, a_cur, V, Vt, out);
}

// Round 9
// 4042.308 us; speedup vs baseline: 2.8194x; 1.0324x over previous
//
#include <hip/hip_runtime.h>
#include <stdint.h>
#include <math.h>

// ============================================================================
// RBM contrastive divergence (K_GIBBS=1), B=64 sequential steps.
// Low-rank restructure: W_t = W0 + LR * sum_{s<t} (v0_s hinit_s^T - v_s hbin_s^T)
//  h_t  = sig(b_t + C[t] + LR*sum_s(hinit_s*G0[s][t] - hbin_s*GV[s][t]))
//  v_t  = sig(a_t + W0 h_t + LR*sum_s(v0_s*(hinit_s.h_t) - v_s*(hbin_s.h_t)))
// C = V0 @ W0 (one GEMM), G0 = V0 V0^T, GV[s][t] = v_s . v0_t.
// Only W0*h_t touches W0 (65 x 201MB total) -> HBM floor ~2.1ms (less w/ L3).
// ============================================================================

#define NB   64
#define FLAT 12288
#define HID  4096
#define LRf  0.01f
#define LRd  0.01
#define RNG_MODE 0

// ---- workspace layout (byte offsets) ----
#define OFF_KEYS   0u          // 64*4 u32
#define OFF_B      1024u       // 4096 f32
#define OFF_A      17408u      // 12288 f32
#define OFF_H      66560u      // 4096 f32
#define OFF_ALP    82944u      // 16*64 f64 block-partial alpha
#define OFF_BEP    91136u      // 16*64 f64 block-partial beta
#define OFF_G0     99328u      // 64*64 f64
#define OFF_GV     132096u     // 64*64 f64
#define OFF_HIB    164864u     // 64*128 u32 hinit bitmasks (row-major)
#define OFF_HBB    197632u     // 64*128 u32 hbin bitmasks (row-major)
#define OFF_C      230400u     // 64*4096 f32
#define OFF_V      1278976u    // 64*12288 f32 (row-major, for k_gv)
#define OFF_VT     4424704u    // 12288*64 f32 (transposed, for gemv correction)
#define OFF_V0T    7570432u    // 12288*64 f32 (transposed v0) — LIVE during cgemm
#define OFF_HIBC   10716160u   // 4096 u64 transposed hinit columns (bit s)
#define OFF_HBBC   10748928u   // 4096 u64 transposed hbin columns
#define OFF_CPART  1278976u    // aliases V+Vt ONLY (6MB: 1278976..7570432).
                               // ROUND-8 BUG: NCH=16 (16MB) overran into v0T
                               // which cgemm v3 READS -> garbage. NCH capped
                               // at 6 so Cpart ends exactly at OFF_V0T.
#define NCH 6                  // 6 chunks x 1MB = 6MB, fits V+Vt alias region

// ---------------------------------------------------------------------------
__device__ __forceinline__ void tf(uint32_t k0, uint32_t k1,
                                   uint32_t x0, uint32_t x1,
                                   uint32_t& o0, uint32_t& o1) {
  uint32_t ks[3] = {k0, k1, k0 ^ k1 ^ 0x1BD11BDAu};
  x0 += ks[0]; x1 += ks[1];
  const int R0[4] = {13, 15, 26, 6};
  const int R1[4] = {17, 29, 16, 24};
#pragma unroll
  for (int i = 0; i < 5; ++i) {
    const int* r = (i & 1) ? R1 : R0;
#pragma unroll
    for (int q = 0; q < 4; ++q) {
      x0 += x1;
      x1 = (x1 << r[q]) | (x1 >> (32 - r[q]));
      x1 ^= x0;
    }
    x0 += ks[(i + 1) % 3];
    x1 += ks[(i + 2) % 3] + (uint32_t)(i + 1);
  }
  o0 = x0; o1 = x1;
}

__device__ __forceinline__ float u01(uint32_t bits) {
  uint32_t fb = (bits >> 9) | 0x3f800000u;
  return __uint_as_float(fb) - 1.0f;
}

// ---------------------------------------------------------------------------
__global__ void k_setup(const float* a_in, const float* b_in,
                        float* a_cur, float* b_cur, uint32_t* keys4) {
  int gid = blockIdx.x * blockDim.x + threadIdx.x;
  int stride = gridDim.x * blockDim.x;
  for (int i = gid; i < FLAT; i += stride) a_cur[i] = a_in[i];
  for (int i = gid; i < HID; i += stride) b_cur[i] = b_in[i];
  if (gid < NB) {
    uint32_t t = (uint32_t)gid;
    uint32_t kt0, kt1, o0, o1, p0, p1;
#if RNG_MODE == 0
    tf(0u, 42u, 0u, t, kt0, kt1);
    tf(kt0, kt1, 0u, 0u, o0, o1);
    tf(kt0, kt1, 0u, 1u, p0, p1);
    keys4[4 * gid + 0] = o0; keys4[4 * gid + 1] = o1;
    keys4[4 * gid + 2] = p0; keys4[4 * gid + 3] = p1;
#else
    if (t < 32) {
      tf(0u, 42u, 2 * t,     64 + 2 * t, o0, o1); kt0 = o0;
      tf(0u, 42u, 2 * t + 1, 65 + 2 * t, o0, o1); kt1 = o0;
    } else {
      tf(0u, 42u, 2 * t - 64, 2 * t,     o0, o1); kt0 = o1;
      tf(0u, 42u, 2 * t - 63, 2 * t + 1, o0, o1); kt1 = o1;
    }
    uint32_t a0, a1, b0, b1;
    tf(kt0, kt1, 0u, 2u, a0, a1);
    tf(kt0, kt1, 1u, 3u, b0, b1);
    keys4[4 * gid + 0] = a0; keys4[4 * gid + 1] = b0;
    keys4[4 * gid + 2] = a1; keys4[4 * gid + 3] = b1;
#endif
  }
}

// v0T[i][s] = v0[s][i]
__global__ void k_vt(const float* v0all, float* v0T) {
  int i = blockIdx.x * 256 + threadIdx.x;
#pragma unroll 8
  for (int s = 0; s < NB; ++s)
    v0T[(size_t)i * NB + s] = v0all[(size_t)s * FLAT + i];
}

// ---------------------------------------------------------------------------
// G0: block per (s,t) pair (4096 blocks) — parallelism over reuse.
// ---------------------------------------------------------------------------
__global__ __launch_bounds__(256) void k_g0(const float* v0all, double* G0) {
  const int t = blockIdx.x, s = blockIdx.y;
  const float4* vs = (const float4*)(v0all + (size_t)s * FLAT);
  const float4* vt = (const float4*)(v0all + (size_t)t * FLAT);
  double acc = 0.0;
  for (int e = threadIdx.x; e < FLAT / 4; e += 256) {
    float4 a = vs[e], b = vt[e];
    acc += (double)a.x * b.x + (double)a.y * b.y +
           (double)a.z * b.z + (double)a.w * b.w;
  }
  for (int m = 32; m; m >>= 1) acc += __shfl_xor(acc, m, 64);
  __shared__ double red[4];
  int wv = threadIdx.x >> 6, lane = threadIdx.x & 63;
  if (lane == 0) red[wv] = acc;
  __syncthreads();
  if (threadIdx.x == 0) G0[s * NB + t] = red[0] + red[1] + red[2] + red[3];
}

// ---------------------------------------------------------------------------
// C partial GEMM v3 (fixed): two-tile LDS GEMM.
//  - W0 tile [64 ii x 64 j] staged in LDS (v2 was latency-bound on redundant
//    scalar global loads: 280us, VALUBusy 19%).
//  - v tile staged from v0T via linear float4 loads (kills v2's 4.7M
//    8-way-conflict staging writes).
//  - FP order per thread unchanged -> C matches v2 modulo creduce NCH split.
// grid (HID/64, NCH), 256 thr = 64 j-lanes x 4 t-groups, 16 acc each.
// ---------------------------------------------------------------------------
__global__ __launch_bounds__(256) void k_cgemm(const float* v0T, const float* W0,
                                               float* Cpart) {
  const int jl = threadIdx.x & 63;
  const int tth = threadIdx.x >> 6;            // 0..3
  const int j0 = blockIdx.x * 64;
  const int ilen = FLAT / NCH;                 // 2048, /64 = 32 tiles
  const int ibeg = blockIdx.y * ilen, iend = ibeg + ilen;
  __shared__ float lv[64 * 68];                // v tile [ii][t], pad 68
  __shared__ float lw[64 * 68];                // W tile [ii][j], pad 68
  float acc[16];
#pragma unroll
  for (int k = 0; k < 16; ++k) acc[k] = 0.f;
  for (int i0 = ibeg; i0 < iend; i0 += 64) {
    __syncthreads();
    // stage v tile: v0T rows are 64 floats -> linear float4, coalesced
    const float4* vsrc = (const float4*)(v0T + (size_t)i0 * NB);
#pragma unroll
    for (int k = 0; k < 4; ++k) {
      int f = threadIdx.x + k * 256;
      int row = f >> 4, c4 = f & 15;
      *(float4*)(&lv[row * 68 + c4 * 4]) = vsrc[f];
    }
    // stage W tile: 256B contiguous per 16-lane group, coalesced
#pragma unroll
    for (int k = 0; k < 4; ++k) {
      int f = threadIdx.x + k * 256;
      int row = f >> 4, c4 = f & 15;
      *(float4*)(&lw[row * 68 + c4 * 4]) =
          *(const float4*)(W0 + (size_t)(i0 + row) * HID + j0 + c4 * 4);
    }
    __syncthreads();
#pragma unroll 2
    for (int ii = 0; ii < 64; ++ii) {
      float w = lw[ii * 68 + jl];              // 2-way bank alias: free
      const float* lp = &lv[ii * 68 + tth * 16];
#pragma unroll
      for (int k4 = 0; k4 < 4; ++k4) {
        float4 hv = *(const float4*)(lp + 4 * k4);   // broadcast read
        acc[4 * k4 + 0] += w * hv.x;
        acc[4 * k4 + 1] += w * hv.y;
        acc[4 * k4 + 2] += w * hv.z;
        acc[4 * k4 + 3] += w * hv.w;
      }
    }
  }
#pragma unroll
  for (int k = 0; k < 16; ++k)
    Cpart[((size_t)blockIdx.y * NB + tth * 16 + k) * HID + j0 + jl] = acc[k];
}

__global__ void k_creduce(const float* Cpart, float* C) {
  int gid = blockIdx.x * blockDim.x + threadIdx.x;
  if (gid >= NB * HID) return;
  double s = 0.0;
  for (int c = 0; c < NCH; ++c) s += (double)Cpart[(size_t)c * NB * HID + gid];
  C[gid] = (float)s;
}

// ---------------------------------------------------------------------------
// Hidden-side, 16 blocks x 256 thr (one j per thread):
//  phase B: h_t from transposed mask COLUMNS (2 u64 loads + ctz loop over set
//           bits, g0c/gvc in LDS).
//  phase C: threefry sample; ballot -> row-mask t; column-bit t; b update.
//  phase D: block-partial alpha/beta dots for s<=t, masks staged in LDS.
// ---------------------------------------------------------------------------
__global__ __launch_bounds__(256) void k_hbc(int t, const float* Call,
                                             const double* G0, const double* GV,
                                             float* b_cur, float* h_cur,
                                             uint32_t* Hib, uint32_t* Hbb,
                                             uint64_t* HibC, uint64_t* HbbC,
                                             double* alp, double* bep,
                                             const uint32_t* keys4) {
  const int tid = threadIdx.x;
  const int lane = tid & 63, wv = tid >> 6;
  const int j = blockIdx.x * 256 + tid;
  __shared__ double g0c[NB], gvc[NB];
  __shared__ float h_blk[256];
  __shared__ unsigned char ib_blk[256], bb_blk[256];
  __shared__ uint32_t ldsI[NB][8], ldsB[NB][8];   // this block's mask words, s<t
  for (int s = tid; s < NB; s += 256) { g0c[s] = G0[s * NB + t]; gvc[s] = GV[s * NB + t]; }
  for (int idx = tid; idx < t * 8; idx += 256) {
    int s = idx >> 3, w = idx & 7;
    ldsI[s][w] = Hib[s * 128 + blockIdx.x * 8 + w];
    ldsB[s][w] = Hbb[s * 128 + blockIdx.x * 8 + w];
  }
  __syncthreads();
  // ---- phase B: logit via transposed columns ----
  uint64_t rawI = (t == 0) ? 0ull : HibC[j];
  uint64_t rawB = (t == 0) ? 0ull : HbbC[j];
  const uint64_t mlow = (t == 0) ? 0ull : ((1ull << t) - 1ull);
  uint64_t mi64 = rawI & mlow, mb64 = rawB & mlow;
  double accp = 0.0, accm = 0.0;
  while (mi64) { int s = __builtin_ctzll(mi64); accp += g0c[s]; mi64 &= mi64 - 1; }
  while (mb64) { int s = __builtin_ctzll(mb64); accm += gvc[s]; mb64 &= mb64 - 1; }
  double lg = (double)b_cur[j] + (double)Call[(size_t)t * HID + j] + LRd * (accp - accm);
  float h = (float)(1.0 / (1.0 + exp(-lg)));
  h_cur[j] = h;
  // ---- phase C: sample ----
  uint32_t o0, o1;
  uint32_t kb0 = keys4[4 * t], kb1 = keys4[4 * t + 1];
  uint32_t ki0 = keys4[4 * t + 2], ki1 = keys4[4 * t + 3];
#if RNG_MODE == 0
  tf(kb0, kb1, 0u, (uint32_t)j, o0, o1); float ub = u01(o0 ^ o1);
  tf(ki0, ki1, 0u, (uint32_t)j, o0, o1); float ui = u01(o0 ^ o1);
#else
  uint32_t m = (uint32_t)(j & (HID / 2 - 1));
  tf(kb0, kb1, m, m + HID / 2, o0, o1); float ub = u01(j < HID / 2 ? o0 : o1);
  tf(ki0, ki1, m, m + HID / 2, o0, o1); float ui = u01(j < HID / 2 ? o0 : o1);
#endif
  bool hb = h > ub, hi = h > ui;
  unsigned long long mb = __ballot(hb), mi = __ballot(hi);
  const int word = j >> 5;
  if (lane == 0) {
    Hbb[t * 128 + word]     = (uint32_t)mb;
    Hbb[t * 128 + word + 1] = (uint32_t)(mb >> 32);
    Hib[t * 128 + word]     = (uint32_t)mi;
    Hib[t * 128 + word + 1] = (uint32_t)(mi >> 32);
  }
  HibC[j] = rawI | ((uint64_t)(hi ? 1 : 0) << t);   // thread j owns word j
  HbbC[j] = rawB | ((uint64_t)(hb ? 1 : 0) << t);
  b_cur[j] += LRf * ((hi ? 1.f : 0.f) - (hb ? 1.f : 0.f));
  h_blk[tid] = h; ib_blk[tid] = hi ? 1 : 0; bb_blk[tid] = hb ? 1 : 0;
  __syncthreads();
  // ---- phase D: block-partial dots, s <= t (masks from LDS) ----
  for (int task = wv; task < 2 * (t + 1); task += 4) {
    int s = task >> 1;
    const bool useB = task & 1;
    double p = 0.0;
#pragma unroll
    for (int q = 0; q < 4; ++q) {
      int jj = q * 64 + lane;
      bool on;
      if (s == t) on = (useB ? bb_blk[jj] : ib_blk[jj]) != 0;
      else {
        uint32_t w32 = useB ? ldsB[s][jj >> 5] : ldsI[s][jj >> 5];
        on = (w32 >> (jj & 31)) & 1u;
      }
      if (on) p += (double)h_blk[jj];
    }
    for (int m2 = 32; m2; m2 >>= 1) p += __shfl_xor(p, m2, 64);
    if (lane == 0) {
      if (useB) bep[(size_t)blockIdx.x * NB + s] = p;
      else      alp[(size_t)blockIdx.x * NB + s] = p;
    }
  }
}

// ---------------------------------------------------------------------------
// Big GEMV: 512 thr, 8 rows/block (wave per row), grid FLAT/8.
// alpha/beta partials reduced once per block (fixed order -> deterministic).
// Correction loads coalesced via v0T/Vt. t==NB: final mode, write d_out.
// ---------------------------------------------------------------------------
__global__ __launch_bounds__(512) void k_gemv(int t, const float* W0,
                                              const float* v0T, const float* h_cur,
                                              const double* alp, const double* bep,
                                              float* a_cur, float* V, float* Vt,
                                              float* out) {
  __shared__ float hs[HID];
  __shared__ double als[NB], bes[NB];
  const int tid = threadIdx.x;
  for (int e = tid; e < HID / 4; e += 512)
    ((float4*)hs)[e] = ((const float4*)h_cur)[e];
  if (tid < NB) {
    double asum = 0.0, bsum = 0.0;
#pragma unroll
    for (int b = 0; b < 16; ++b) {
      asum += alp[(size_t)b * NB + tid];
      bsum += bep[(size_t)b * NB + tid];
    }
    als[tid] = asum; bes[tid] = bsum;
  }
  __syncthreads();
  const int wv = tid >> 6, lane = tid & 63;
  const int row = blockIdx.x * 8 + wv;
  const float4* wr = (const float4*)(W0 + (size_t)row * HID);
  double acc = 0.0;
#pragma unroll
  for (int c = 0; c < 16; ++c) {
    float4 w = wr[c * 64 + lane];
    float4 hh = ((const float4*)hs)[c * 64 + lane];
    acc += (double)w.x * hh.x + (double)w.y * hh.y +
           (double)w.z * hh.z + (double)w.w * hh.w;
  }
  const int smax = (t > NB - 1) ? NB : t;
  if (lane < smax) {
    double c = (double)v0T[(size_t)row * NB + lane] * als[lane]
             - (double)Vt[(size_t)row * NB + lane] * bes[lane];
    acc += LRd * c;
  }
  for (int m = 32; m; m >>= 1) acc += __shfl_xor(acc, m, 64);
  if (lane == 0) {
    double lg = (double)a_cur[row] + acc;
    float v = (float)(1.0 / (1.0 + exp(-lg)));
    if (t == NB) {
      out[row] = v;
    } else {
      V[(size_t)t * FLAT + row] = v;
      Vt[(size_t)row * NB + t] = v;
      a_cur[row] += LRf * (v0T[(size_t)row * NB + t] - v);
    }
  }
}

// ---------------------------------------------------------------------------
// GV row t: GV[t][t'] = v_t . v0_t' for t' > t (block per t'), float4.
// ---------------------------------------------------------------------------
__global__ void k_gv(int t, const float* v0all, const float* V, double* GV) {
  int tp = t + 1 + blockIdx.x;
  const float4* vt = (const float4*)(V + (size_t)t * FLAT);
  const float4* v0 = (const float4*)(v0all + (size_t)tp * FLAT);
  double acc = 0.0;
  for (int e = threadIdx.x; e < FLAT / 4; e += 256) {
    float4 a = vt[e], b = v0[e];
    acc += (double)a.x * b.x + (double)a.y * b.y +
           (double)a.z * b.z + (double)a.w * b.w;
  }
  for (int m = 32; m; m >>= 1) acc += __shfl_xor(acc, m, 64);
  __shared__ double red[4];
  int wv = threadIdx.x >> 6, lane = threadIdx.x & 63;
  if (lane == 0) red[wv] = acc;
  __syncthreads();
  if (threadIdx.x == 0) GV[t * NB + tp] = red[0] + red[1] + red[2] + red[3];
}

// ---------------------------------------------------------------------------
extern "C" void kernel_launch(void* const* d_in, const int* in_sizes, int n_in,
                              void* d_out, int out_size, void* d_ws, size_t ws_size,
                              hipStream_t stream) {
  const float* inputs = (const float*)d_in[0];
  const float* W0     = (const float*)d_in[1];
  const float* a_in   = (const float*)d_in[2];
  const float* b_in   = (const float*)d_in[3];
  float* out = (float*)d_out;

  char* ws = (char*)d_ws;
  uint32_t* keys4 = (uint32_t*)(ws + OFF_KEYS);
  float* b_cur = (float*)(ws + OFF_B);
  float* a_cur = (float*)(ws + OFF_A);
  float* h_cur = (float*)(ws + OFF_H);
  double* alp  = (double*)(ws + OFF_ALP);
  double* bep  = (double*)(ws + OFF_BEP);
  double* G0   = (double*)(ws + OFF_G0);
  double* GV   = (double*)(ws + OFF_GV);
  uint32_t* Hib = (uint32_t*)(ws + OFF_HIB);
  uint32_t* Hbb = (uint32_t*)(ws + OFF_HBB);
  uint64_t* HibC = (uint64_t*)(ws + OFF_HIBC);
  uint64_t* HbbC = (uint64_t*)(ws + OFF_HBBC);
  float* C     = (float*)(ws + OFF_C);
  float* V     = (float*)(ws + OFF_V);
  float* Vt    = (float*)(ws + OFF_VT);
  float* v0T   = (float*)(ws + OFF_V0T);
  float* Cpart = (float*)(ws + OFF_CPART);   // aliases V+Vt only (6MB);
                                             // ends exactly at OFF_V0T

  hipLaunchKernelGGL(k_setup, dim3(48), dim3(256), 0, stream,
                     a_in, b_in, a_cur, b_cur, keys4);
  hipLaunchKernelGGL(k_g0, dim3(NB, NB), dim3(256), 0, stream, inputs, G0);
  hipLaunchKernelGGL(k_vt, dim3(FLAT / 256), dim3(256), 0, stream, inputs, v0T);
  hipLaunchKernelGGL(k_cgemm, dim3(HID / 64, NCH), dim3(256), 0, stream,
                     v0T, W0, Cpart);
  hipLaunchKernelGGL(k_creduce, dim3((NB * HID + 255) / 256), dim3(256), 0,
                     stream, Cpart, C);

  for (int t = 0; t < NB; ++t) {
    hipLaunchKernelGGL(k_hbc, dim3(HID / 256), dim3(256), 0, stream,
                       t, C, G0, GV, b_cur, h_cur, Hib, Hbb, HibC, HbbC,
                       alp, bep, keys4);
    hipLaunchKernelGGL(k_gemv, dim3(FLAT / 8), dim3(512), 0, stream,
                       t, W0, v0T, h_cur, alp, bep, a_cur, V, Vt, out);
    if (t < NB - 1)
      hipLaunchKernelGGL(k_gv, dim3(NB - 1 - t), dim3(256), 0, stream,
                         t, inputs, V, GV);
  }
  // final: v = sig(a_64 + W_64 h_63); alpha/beta for s<=63 already from k_hbc(63)
  hipLaunchKernelGGL(k_gemv, dim3(FLAT / 8), dim3(512), 0, stream,
                     NB, W0, v0T, h_cur, alp, bep, a_cur, V, Vt, out);
}